// Round 12
// baseline (460.073 us; speedup 1.0000x reference)
//
#include <hip/hip_runtime.h>
#include <hip/hip_bf16.h>

// Corr: B=4, C=256, H=W=64, HW=4096, TOPK=3, rat_s=0.05 -> sigma=3.2, 2*sigma^2=20.48
// s[m,n] = alpha * (1 - exp(-(dr^2+dc^2)/20.48)) * <xn_m, xn_n>  (symmetric)
// xc[m,n] = exp(2 s[m,n]) / (sm[m] sm[n]),  sm[m] = sum_n exp(s[m,n])
// out[b,k,col] = top-3 over m of xc[m,col]
//
// R1..R9: XCD<->batch binding, log-domain top-k, non-atomic partials, k-slot
//   swizzle, triangular dual-direction topk, __syncthreads K-loop (raw vmcnt
//   barriers w/ LDS-DMA: numerically unsafe -> banned), odd-stride rtop.
// R10 (REVERTED): hipLaunchCooperativeKernel silently failed to launch
//   (all-zero output) -> cooperative launch banned in this harness.
// R11: persistent kernel, ORDINARY launch <<<512,256>>>, software grid barrier
//   (device-scope atomic generation counter + __threadfence). Residency
//   guaranteed: __launch_bounds__(256,2) + 32KB LDS -> >=2 blocks/CU -> all
//   512 blocks co-resident -> spin barrier deadlock-free. Counter in d_ws at
//   an offset proven in-bounds by R2's accepted layout; memset each call.

#define HW 4096
#define CDIM 256
#define INV2S2 0.048828125f  // 1/20.48
#define NEGINF -1e30f
#define NTILE 528
#define NWORK_GEMM (NTILE * 4)  // 2112
#define GRID 512

typedef __bf16 bf16;
typedef __attribute__((ext_vector_type(8))) __bf16 bf16x8;
typedef __attribute__((ext_vector_type(4))) float f32x4;

#define GAS __attribute__((address_space(1)))
#define LAS __attribute__((address_space(3)))

__device__ __forceinline__ void ins3(float v, float& t0, float& t1, float& t2) {
    // maintains t0>=t1>=t2; exact top-3 insert in 3 VALU ops (v_max + 2x v_med3)
    float n0 = fmaxf(t0, v);
    float n1 = __builtin_amdgcn_fmed3f(t0, t1, v);
    float n2 = __builtin_amdgcn_fmed3f(t1, t2, v);
    t0 = n0; t1 = n1; t2 = n2;
}

// software grid barrier: generation counter, target = gen * GRID. Never reset
// in-kernel; host memsets to 0 before each launch (captured in the graph).
__device__ __forceinline__ void gbarrier(int* cnt, int target) {
    __syncthreads();
    if (threadIdx.x == 0) {
        __threadfence();  // release: make this block's writes device-visible
        __hip_atomic_fetch_add(cnt, 1, __ATOMIC_RELEASE, __HIP_MEMORY_SCOPE_AGENT);
        while (__hip_atomic_load(cnt, __ATOMIC_ACQUIRE, __HIP_MEMORY_SCOPE_AGENT) < target)
            __builtin_amdgcn_s_sleep(8);
        __threadfence();  // acquire: invalidate stale cached lines
    }
    __syncthreads();
}

// triangular decode: t = mt*(mt+1)/2 + nt, nt <= mt
__device__ __forceinline__ void decode_tri(int t, int& mt, int& nt) {
    int m = (int)((sqrtf(8.f * (float)t + 1.f) - 1.f) * 0.5f);
    while ((m + 1) * (m + 2) / 2 <= t) ++m;
    while (m * (m + 1) / 2 > t) --m;
    mt = m;
    nt = t - m * (m + 1) / 2;
}

// ---------------- GEMM tile core: 128x128, K=256, dbuf single-barrier, k-slot swizzle ----
__device__ __forceinline__ void gemm_tile(const bf16* __restrict__ xb, int mbase, int nbase,
                                          bf16* As, bf16* Bs, f32x4 (&acc)[4][4]) {
    const int tid = threadIdx.x;
    const int wave = tid >> 6;
    const int lane = tid & 63;
    const int wm = wave >> 1, wn = wave & 1;
    const int l15 = lane & 15, quad = lane >> 4;
#pragma unroll
    for (int mi = 0; mi < 4; ++mi)
#pragma unroll
        for (int ni = 0; ni < 4; ++ni) acc[mi][ni] = (f32x4)0.f;

    auto issue = [&](int kk, int buf) {
#pragma unroll
        for (int r = 0; r < 2; ++r) {
            int idx = r * 256 + tid;
            int prow = idx >> 2;
            int sub = ((idx & 3) - (prow >> 1)) & 3;  // swizzled k-group
            const bf16* gA = xb + ((size_t)(mbase + prow) << 8) + kk * 32 + (sub << 3);
            const bf16* gB = xb + ((size_t)(nbase + prow) << 8) + kk * 32 + (sub << 3);
            bf16* lA = As + buf * 4096 + ((r * 4 + wave) << 9);
            bf16* lB = Bs + buf * 4096 + ((r * 4 + wave) << 9);
            __builtin_amdgcn_global_load_lds((const GAS void*)gA, (LAS void*)lA, 16, 0, 0);
            __builtin_amdgcn_global_load_lds((const GAS void*)gB, (LAS void*)lB, 16, 0, 0);
        }
    };
    issue(0, 0);
    const int rslot = ((quad + (l15 >> 1)) & 3) * 8;
#pragma unroll
    for (int kk = 0; kk < 8; ++kk) {
        __syncthreads();
        if (kk < 7) issue(kk + 1, (kk + 1) & 1);
        int buf = kk & 1;
        bf16x8 af[4], bfr[4];
#pragma unroll
        for (int i = 0; i < 4; ++i) {
            af[i]  = *(const bf16x8*)(As + buf * 4096 + (wm * 64 + i * 16 + l15) * 32 + rslot);
            bfr[i] = *(const bf16x8*)(Bs + buf * 4096 + (wn * 64 + i * 16 + l15) * 32 + rslot);
        }
#pragma unroll
        for (int mi = 0; mi < 4; ++mi)
#pragma unroll
            for (int ni = 0; ni < 4; ++ni)
                acc[mi][ni] = __builtin_amdgcn_mfma_f32_16x16x32_bf16(af[mi], bfr[ni],
                                                                      acc[mi][ni], 0, 0, 0);
    }
    // post-loop: iter-7 reads hit buf1 only; buf0 regions are dead -> epilogue scratch.
}

// extw[j] = scale*(1 - exp(-(adr^2+(j-63)^2)/20.48)), j in [0,128) — wave-private
__device__ __forceinline__ void build_ext(float* extw, int lane, int adr, float scale) {
    float fr2 = (float)(adr * adr);
#pragma unroll
    for (int h = 0; h < 2; ++h) {
        int j = lane + h * 64;
        float d = (float)(j - 63);
        extw[j] = scale * (1.f - __expf(-(fr2 + d * d) * INV2S2));
    }
}

// per-lane register table e[dm][r], dm = mi-ni+3
__device__ __forceinline__ void load_etab(const float* extw_wave, int quad, int l15,
                                          float (&e)[7][4]) {
    const float* p = extw_wave + 63 + quad * 4 - l15;
#pragma unroll
    for (int dm = 0; dm < 7; ++dm)
#pragma unroll
        for (int r = 0; r < 4; ++r) e[dm][r] = p[(dm - 3) * 16 + r];
}

// ---------------- phase 1: normalize + transpose (fits 32KB SH via 2 half-rounds) ---------
__device__ __forceinline__ void norm_phase(int wid, const float* __restrict__ x,
                                           bf16* __restrict__ xnT, bf16* SH) {
    float* F = (float*)SH;
    float* red  = F;        // [4][64]   bytes 0..1023
    float* invn = F + 256;  // [64]      bytes 1024..1279
    bf16* T = SH + 4096;    // [64][136] bf16, bytes 8192..25599
    int tid = threadIdx.x;
    int pl = tid & 63, cg = tid >> 6;
    int P0 = wid * 64;
    int P = P0 + pl;
    int b = P >> 12;
    int pix = P & 4095;
    const float* xb = x + ((size_t)(b * CDIM + cg * 64) << 12) + pix;
    float v[64];
    float ss = 0.f;
#pragma unroll
    for (int j = 0; j < 64; ++j) {
        v[j] = xb[(size_t)j << 12];
        ss += v[j] * v[j];
    }
    red[cg * 64 + pl] = ss;
    __syncthreads();
    if (tid < 64) {
        float s = red[tid] + red[64 + tid] + red[128 + tid] + red[192 + tid];
        invn[tid] = 1.0f / fmaxf(sqrtf(s), 1e-12f);
    }
    __syncthreads();
    float inv = invn[pl];
#pragma unroll
    for (int h = 0; h < 2; ++h) {
        if ((cg >> 1) == h) {
            int base = (cg & 1) * 64;
#pragma unroll
            for (int j0 = 0; j0 < 64; j0 += 8) {
                bf16x8 pk;
#pragma unroll
                for (int j = 0; j < 8; ++j) pk[j] = (bf16)(v[j0 + j] * inv);
                *(bf16x8*)(T + pl * 136 + base + j0) = pk;
            }
        }
        __syncthreads();
        // write out: lanes sweep channels -> contiguous 256B per pixel
#pragma unroll
        for (int it = 0; it < 4; ++it) {
            int p = it * 16 + (tid >> 4);
            int k = tid & 15;
            bf16x8 val = *(const bf16x8*)(T + p * 136 + k * 8);
            *(bf16x8*)(xnT + (size_t)(P0 + p) * CDIM + h * 128 + k * 8) = val;
        }
        __syncthreads();
    }
}

// ---------------- phase 2: rowsum partials, triangular tiles, no atomics ----------------
__device__ __forceinline__ void rowsum_phase(int lin, const bf16* __restrict__ xnT,
                                             const float* __restrict__ alpha_p,
                                             float* __restrict__ rpart, bf16* SH) {
    bf16* As = SH;
    bf16* Bs = SH + 8192;
    int tid = threadIdx.x;
    int xcd = lin & 7;
    int b = xcd >> 1;
    int t = ((lin >> 3) << 1) + (xcd & 1);  // [0, 528)
    int mt, nt;
    decode_tri(t, mt, nt);
    int mbase = mt * 128, nbase = nt * 128;
    int wave = tid >> 6, lane = tid & 63;
    int wm = wave >> 1, wn = wave & 1, l15 = lane & 15, quad = lane >> 4;
    int rowi = (mbase + wm * 64) >> 6;
    int coli = (nbase + wn * 64) >> 6;
    int adr = rowi - coli; if (adr < 0) adr = -adr;
    float alpha = alpha_p[0];

    f32x4 acc[4][4];
    gemm_tile(xnT + ((size_t)b << 20), mbase, nbase, As, Bs, acc);

    float* F = (float*)SH;
    float* ext  = F;              // [4][128] wave-private (dead As-buf0)
    float* rbuf = F + 512;        // [2][128]
    float* cbuf = F + 768;        // [2][128]
    build_ext(ext + wave * 128, lane, adr, alpha);
    float e[7][4];
    load_etab(ext + wave * 128, quad, l15, e);

    float colpart[4] = {0.f, 0.f, 0.f, 0.f};
#pragma unroll
    for (int mi = 0; mi < 4; ++mi) {
#pragma unroll
        for (int r = 0; r < 4; ++r) {
            float ssum = 0.f;
#pragma unroll
            for (int ni = 0; ni < 4; ++ni) {
                float s = e[mi - ni + 3][r] * acc[mi][ni][r];
                float ev = __expf(s);
                ssum += ev;
                colpart[ni] += ev;
            }
            ssum += __shfl_xor(ssum, 1);
            ssum += __shfl_xor(ssum, 2);
            ssum += __shfl_xor(ssum, 4);
            ssum += __shfl_xor(ssum, 8);
            if (l15 == 0) rbuf[wn * 128 + wm * 64 + mi * 16 + quad * 4 + r] = ssum;
        }
    }
#pragma unroll
    for (int ni = 0; ni < 4; ++ni) {
        float c = colpart[ni];
        c += __shfl_xor(c, 16);
        c += __shfl_xor(c, 32);
        if (quad == 0) cbuf[wm * 128 + wn * 64 + ni * 16 + l15] = c;
    }
    __syncthreads();
    if (tid < 128) {
        rpart[(size_t)((b * 32 + mt) * 32 + nt) * 128 + tid] = rbuf[tid] + rbuf[128 + tid];
    } else if (mt != nt) {
        int j = tid - 128;
        rpart[(size_t)((b * 32 + nt) * 32 + mt) * 128 + j] = cbuf[j] + cbuf[128 + j];
    }
    __syncthreads();  // protect SH before next loop iteration reuses it
}

// ---------------- phase 3: slot-reduce + reciprocal + negative log ----------------
__device__ __forceinline__ void recip_phase(int wid, const float* __restrict__ rpart,
                                            float* __restrict__ ism, float* __restrict__ lsm) {
    int i = wid * 256 + threadIdx.x;
    int b = i >> 12, gr = i & 4095, s = gr >> 7, j = gr & 127;
    const float* base = rpart + (size_t)((b * 32 + s) * 32) * 128 + j;
    float sum = 0.f;
#pragma unroll
    for (int sl = 0; sl < 32; ++sl) sum += base[sl * 128];
    ism[i] = 1.0f / sum;
    lsm[i] = -__logf(sum);
}

// ---------------- phase 4: triangular log-domain top-3, dual direction ----------------
__device__ __forceinline__ void topk_phase(int lin, const bf16* __restrict__ xnT,
                                           const float* __restrict__ alpha_p,
                                           const float* __restrict__ lsm,
                                           float* __restrict__ wtop, bf16* SH) {
    bf16* As = SH;
    bf16* Bs = SH + 8192;
    int tid = threadIdx.x;
    int xcd = lin & 7;
    int b = xcd >> 1;
    int t = ((lin >> 3) << 1) + (xcd & 1);  // [0, 528)
    int mt, nt;
    decode_tri(t, mt, nt);
    int mbase = mt * 128, nbase = nt * 128;
    int wave = tid >> 6, lane = tid & 63;
    int wm = wave >> 1, wn = wave & 1, l15 = lane & 15, quad = lane >> 4;
    int rowi = (mbase + wm * 64) >> 6;
    int coli = (nbase + wn * 64) >> 6;
    int adr = rowi - coli; if (adr < 0) adr = -adr;
    float a2 = 2.0f * alpha_p[0];

    f32x4 acc[4][4];
    gemm_tile(xnT + ((size_t)b << 20), mbase, nbase, As, Bs, acc);

    float* F = (float*)SH;
    float* ext  = F;              // [4][128]            floats 0..511 (dead buf0)
    float* mbuf = F + 512;        // [2][128][3]         floats 512..1279
    float* rtop = F + 1280;       // [128][51]: odd stride -> full bank spread
    build_ext(ext + wave * 128, lane, adr, a2);
    float e[7][4];
    load_etab(ext + wave * 128, quad, l15, e);

    float lr[4][4];
#pragma unroll
    for (int mi = 0; mi < 4; ++mi)
#pragma unroll
        for (int r = 0; r < 4; ++r)
            lr[mi][r] = lsm[(b << 12) + mbase + wm * 64 + mi * 16 + quad * 4 + r];
    float lc[4];
#pragma unroll
    for (int ni = 0; ni < 4; ++ni)
        lc[ni] = lsm[(b << 12) + nbase + wn * 64 + ni * 16 + l15];

    // ---- column direction: top3 over rows for each tile column ----
#pragma unroll
    for (int ni = 0; ni < 4; ++ni) {
        float t0 = NEGINF, t1 = NEGINF, t2 = NEGINF;
#pragma unroll
        for (int mi = 0; mi < 4; ++mi) {
#pragma unroll
            for (int r = 0; r < 4; ++r) {
                float key = fmaf(e[mi - ni + 3][r], acc[mi][ni][r], lr[mi][r]);
                ins3(key, t0, t1, t2);
            }
        }
#pragma unroll
        for (int d = 16; d <= 32; d <<= 1) {
            float s0 = __shfl_xor(t0, d);
            float s1 = __shfl_xor(t1, d);
            float s2 = __shfl_xor(t2, d);
            ins3(s0, t0, t1, t2);
            ins3(s1, t0, t1, t2);
            ins3(s2, t0, t1, t2);
        }
        if (quad == 0) {
            int cl = wn * 64 + ni * 16 + l15;
            mbuf[(wm * 128 + cl) * 3 + 0] = t0;
            mbuf[(wm * 128 + cl) * 3 + 1] = t1;
            mbuf[(wm * 128 + cl) * 3 + 2] = t2;
        }
    }
    __syncthreads();  // GEMM LDS reads done -> rtop region reusable

    // ---- row direction (xc[c,n]=xc[n,c]): top3 over cols for each tile row ----
    if (mt != nt) {
#pragma unroll
        for (int mi = 0; mi < 4; ++mi) {
#pragma unroll
            for (int r = 0; r < 4; ++r) {
                float u0 = NEGINF, u1 = NEGINF, u2 = NEGINF;
#pragma unroll
                for (int ni = 0; ni < 4; ++ni) {
                    float key = fmaf(e[mi - ni + 3][r], acc[mi][ni][r], lc[ni]);
                    ins3(key, u0, u1, u2);
                }
                {
                    float s0 = __shfl_xor(u0, 8);
                    float s1 = __shfl_xor(u1, 8);
                    float s2 = __shfl_xor(u2, 8);
                    ins3(s0, u0, u1, u2);
                    ins3(s1, u0, u1, u2);
                    ins3(s2, u0, u1, u2);
                }
                if (l15 < 8) {
                    int row = wm * 64 + mi * 16 + quad * 4 + r;
                    int slot = wn * 8 + l15;
                    float* q = rtop + row * 51 + slot * 3;
                    q[0] = u0; q[1] = u1; q[2] = u2;
                }
            }
        }
    }
    __syncthreads();
    if (tid < 128) {
        // column-direction merge: strip nt, slot mt, column nbase+tid
        float t0 = mbuf[tid * 3], t1 = mbuf[tid * 3 + 1], t2 = mbuf[tid * 3 + 2];
        ins3(mbuf[(128 + tid) * 3 + 0], t0, t1, t2);
        ins3(mbuf[(128 + tid) * 3 + 1], t0, t1, t2);
        ins3(mbuf[(128 + tid) * 3 + 2], t0, t1, t2);
        size_t o = ((size_t)((b * 32 + nt) * 32 + mt) * 128 + tid) * 3;
        wtop[o] = t0;
        wtop[o + 1] = t1;
        wtop[o + 2] = t2;
        if (mt != nt) {
            float v0 = NEGINF, v1 = NEGINF, v2 = NEGINF;
            const float* q = rtop + tid * 51;
#pragma unroll
            for (int sl = 0; sl < 16; ++sl) {
                ins3(q[sl * 3 + 0], v0, v1, v2);
                ins3(q[sl * 3 + 1], v0, v1, v2);
                ins3(q[sl * 3 + 2], v0, v1, v2);
            }
            size_t o2 = ((size_t)((b * 32 + mt) * 32 + nt) * 128 + tid) * 3;
            wtop[o2] = v0;
            wtop[o2 + 1] = v1;
            wtop[o2 + 2] = v2;
        }
    }
    __syncthreads();  // protect SH before next loop iteration reuses it
}

// ---------------- phase 5: final merge; exp + column scale ----------------
__device__ __forceinline__ void merge_phase(int wid, const float* __restrict__ wtop,
                                            const float* __restrict__ ism,
                                            float* __restrict__ out) {
    int idx = wid * 256 + threadIdx.x;
    int b = idx >> 12, col = idx & 4095;
    int strip = col >> 7, j = col & 127;
    const float* base = wtop + ((size_t)((b * 32 + strip) * 32) * 128 + j) * 3;
    float t0 = NEGINF, t1 = NEGINF, t2 = NEGINF;
    for (int sl = 0; sl < 32; ++sl) {
        const float* q = base + (size_t)sl * 128 * 3;
        ins3(q[0], t0, t1, t2);
        ins3(q[1], t0, t1, t2);
        ins3(q[2], t0, t1, t2);
    }
    float ismc = ism[idx];
    out[((b * 3 + 0) << 12) + col] = __expf(t0) * ismc;
    out[((b * 3 + 1) << 12) + col] = __expf(t1) * ismc;
    out[((b * 3 + 2) << 12) + col] = __expf(t2) * ismc;
}

// ---------------- the single persistent kernel (ordinary launch) ----------------
__global__ __launch_bounds__(256, 2) void corr_all(const float* __restrict__ x,
                                                   const float* __restrict__ alpha_p,
                                                   bf16* __restrict__ xnT,
                                                   float* __restrict__ rpart,  // aliases wtop
                                                   float* __restrict__ ism,
                                                   float* __restrict__ lsm,
                                                   float* __restrict__ wtop,
                                                   float* __restrict__ out,
                                                   int* __restrict__ cnt) {
    __shared__ __align__(16) bf16 SH[16384];  // 32KB, reused by every phase
    // stride GRID (mult of 8) -> w%8 == blockIdx.x%8: XCD<->batch binding kept
    for (int w = blockIdx.x; w < 256; w += GRID) norm_phase(w, x, xnT, SH);
    gbarrier(cnt, 1 * GRID);
    for (int w = blockIdx.x; w < NWORK_GEMM; w += GRID) rowsum_phase(w, xnT, alpha_p, rpart, SH);
    gbarrier(cnt, 2 * GRID);
    for (int w = blockIdx.x; w < 64; w += GRID) recip_phase(w, rpart, ism, lsm);
    gbarrier(cnt, 3 * GRID);
    for (int w = blockIdx.x; w < NWORK_GEMM; w += GRID) topk_phase(w, xnT, alpha_p, lsm, wtop, SH);
    gbarrier(cnt, 4 * GRID);
    for (int w = blockIdx.x; w < 64; w += GRID) merge_phase(w, wtop, ism, out);
}

extern "C" void kernel_launch(void* const* d_in, const int* in_sizes, int n_in,
                              void* d_out, int out_size, void* d_ws, size_t ws_size,
                              hipStream_t stream) {
    const float* x = (const float*)d_in[0];
    const float* alpha = (const float*)d_in[1];
    float* out = (float*)d_out;
    char* ws = (char*)d_ws;
    bf16* xnT = (bf16*)ws;                                    // 8 MB
    float* ism = (float*)(ws + (8u << 20));                   // 64 KB
    float* lsm = (float*)(ws + (8u << 20) + (64u << 10));     // 64 KB
    // rpart (2 MB) and wtop (6 MB) alias: disjoint lifetimes across barriers.
    float* rpart = (float*)(ws + (8u << 20) + (128u << 10));
    float* wtop  = (float*)(ws + (8u << 20) + (128u << 10));
    // barrier counter right after wtop; total use = R2-proven footprint + 64B.
    int* cnt = (int*)(ws + (8u << 20) + (128u << 10) + (6u << 20));

    hipMemsetAsync(cnt, 0, 64, stream);
    corr_all<<<GRID, 256, 0, stream>>>(x, alpha, xnT, rpart, ism, lsm, wtop, out, cnt);
}

// Round 13
// 260.478 us; speedup vs baseline: 1.7663x; 1.7663x over previous
//
#include <hip/hip_runtime.h>
#include <hip/hip_bf16.h>

// Corr: B=4, C=256, H=W=64, HW=4096, TOPK=3, rat_s=0.05 -> sigma=3.2, 2*sigma^2=20.48
// s[m,n] = alpha * (1 - exp(-(dr^2+dc^2)/20.48)) * <xn_m, xn_n>  (symmetric)
// xc[m,n] = exp(2 s[m,n]) / (sm[m] sm[n]),  sm[m] = sum_n exp(s[m,n])
// out[b,k,col] = top-3 over m of xc[m,col]
//
// R1..R9: XCD<->batch binding, log-domain top-k, non-atomic partials, k-slot
//   swizzle, triangular dual-direction topk, __syncthreads K-loop, odd-stride
//   rtop, LDS-transposed norm.
// BANNED (measured failures): raw vmcnt barriers w/ LDS-DMA (R7: absmax 7e-8),
//   hipLaunchCooperativeKernel (R10: never ran), persistent spin barrier
//   (R11: ACQUIRE-spin invalidated XCD L2 per poll -> 3x regression).
// R12: last-block-FINISHER fusion (no spinning): recip folded into rowsum,
//   merge folded into topk via per-strip device atomic counters. 1 release
//   fence per block, 1 acquire fence per finisher (128/pass, end-clustered).
//   Finisher loops copy recip/merge verbatim -> bit-identical output.

#define HW 4096
#define CDIM 256
#define INV2S2 0.048828125f  // 1/20.48
#define NEGINF -1e30f
#define NTILE 528

typedef __bf16 bf16;
typedef __attribute__((ext_vector_type(8))) __bf16 bf16x8;
typedef __attribute__((ext_vector_type(4))) float f32x4;

#define GAS __attribute__((address_space(1)))
#define LAS __attribute__((address_space(3)))

__device__ __forceinline__ void ins3(float v, float& t0, float& t1, float& t2) {
    // maintains t0>=t1>=t2; exact top-3 insert in 3 VALU ops (v_max + 2x v_med3)
    float n0 = fmaxf(t0, v);
    float n1 = __builtin_amdgcn_fmed3f(t0, t1, v);
    float n2 = __builtin_amdgcn_fmed3f(t1, t2, v);
    t0 = n0; t1 = n1; t2 = n2;
}

// triangular decode: t = mt*(mt+1)/2 + nt, nt <= mt
__device__ __forceinline__ void decode_tri(int t, int& mt, int& nt) {
    int m = (int)((sqrtf(8.f * (float)t + 1.f) - 1.f) * 0.5f);
    while ((m + 1) * (m + 2) / 2 <= t) ++m;
    while (m * (m + 1) / 2 > t) --m;
    mt = m;
    nt = t - m * (m + 1) / 2;
}

// ---------------- normalize + transpose to bf16 xnT[b][pixel][channel] ----------------
__global__ __launch_bounds__(256) void corr_norm(const float* __restrict__ x,
                                                 bf16* __restrict__ xnT) {
    __shared__ float red[4][64];
    __shared__ float invn[64];
    __shared__ __align__(16) bf16 T[64][264];  // 264 = 256 + 8 pad
    int tid = threadIdx.x;
    int pl = tid & 63, cg = tid >> 6;
    int P0 = blockIdx.x * 64;
    int P = P0 + pl;
    int b = P >> 12;
    int pix = P & 4095;
    const float* xb = x + ((size_t)(b * CDIM + cg * 64) << 12) + pix;
    float v[64];
    float ss = 0.f;
#pragma unroll
    for (int j = 0; j < 64; ++j) {
        v[j] = xb[(size_t)j << 12];
        ss += v[j] * v[j];
    }
    red[cg][pl] = ss;
    __syncthreads();
    if (tid < 64) {
        float s = red[0][tid] + red[1][tid] + red[2][tid] + red[3][tid];
        invn[tid] = 1.0f / fmaxf(sqrtf(s), 1e-12f);
    }
    __syncthreads();
    float inv = invn[pl];
#pragma unroll
    for (int j0 = 0; j0 < 64; j0 += 8) {
        bf16x8 pk;
#pragma unroll
        for (int j = 0; j < 8; ++j) pk[j] = (bf16)(v[j0 + j] * inv);
        *(bf16x8*)(&T[pl][cg * 64 + j0]) = pk;
    }
    __syncthreads();
    // write out: lanes sweep channels -> contiguous 512B per pixel, 8 pixels/iter
#pragma unroll
    for (int it = 0; it < 8; ++it) {
        int p = it * 8 + (tid >> 5);
        int k = tid & 31;
        bf16x8 val = *(const bf16x8*)(&T[p][k * 8]);
        *(bf16x8*)(xnT + (size_t)(P0 + p) * CDIM + k * 8) = val;
    }
}

// ---------------- GEMM tile core: 128x128, K=256, dbuf single-barrier, k-slot swizzle ----
__device__ __forceinline__ void gemm_tile(const bf16* __restrict__ xb, int mbase, int nbase,
                                          bf16* As, bf16* Bs, f32x4 (&acc)[4][4]) {
    const int tid = threadIdx.x;
    const int wave = tid >> 6;
    const int lane = tid & 63;
    const int wm = wave >> 1, wn = wave & 1;
    const int l15 = lane & 15, quad = lane >> 4;
#pragma unroll
    for (int mi = 0; mi < 4; ++mi)
#pragma unroll
        for (int ni = 0; ni < 4; ++ni) acc[mi][ni] = (f32x4)0.f;

    auto issue = [&](int kk, int buf) {
#pragma unroll
        for (int r = 0; r < 2; ++r) {
            int idx = r * 256 + tid;
            int prow = idx >> 2;
            int sub = ((idx & 3) - (prow >> 1)) & 3;  // swizzled k-group
            const bf16* gA = xb + ((size_t)(mbase + prow) << 8) + kk * 32 + (sub << 3);
            const bf16* gB = xb + ((size_t)(nbase + prow) << 8) + kk * 32 + (sub << 3);
            bf16* lA = As + buf * 4096 + ((r * 4 + wave) << 9);
            bf16* lB = Bs + buf * 4096 + ((r * 4 + wave) << 9);
            __builtin_amdgcn_global_load_lds((const GAS void*)gA, (LAS void*)lA, 16, 0, 0);
            __builtin_amdgcn_global_load_lds((const GAS void*)gB, (LAS void*)lB, 16, 0, 0);
        }
    };
    issue(0, 0);
    const int rslot = ((quad + (l15 >> 1)) & 3) * 8;
#pragma unroll
    for (int kk = 0; kk < 8; ++kk) {
        __syncthreads();
        if (kk < 7) issue(kk + 1, (kk + 1) & 1);
        int buf = kk & 1;
        bf16x8 af[4], bfr[4];
#pragma unroll
        for (int i = 0; i < 4; ++i) {
            af[i]  = *(const bf16x8*)(As + buf * 4096 + (wm * 64 + i * 16 + l15) * 32 + rslot);
            bfr[i] = *(const bf16x8*)(Bs + buf * 4096 + (wn * 64 + i * 16 + l15) * 32 + rslot);
        }
#pragma unroll
        for (int mi = 0; mi < 4; ++mi)
#pragma unroll
            for (int ni = 0; ni < 4; ++ni)
                acc[mi][ni] = __builtin_amdgcn_mfma_f32_16x16x32_bf16(af[mi], bfr[ni],
                                                                      acc[mi][ni], 0, 0, 0);
    }
    // post-loop: iter-7 reads hit buf1 only; buf0 regions are dead -> epilogue scratch.
}

// extw[j] = scale*(1 - exp(-(adr^2+(j-63)^2)/20.48)), j in [0,128) — wave-private
__device__ __forceinline__ void build_ext(float* extw, int lane, int adr, float scale) {
    float fr2 = (float)(adr * adr);
#pragma unroll
    for (int h = 0; h < 2; ++h) {
        int j = lane + h * 64;
        float d = (float)(j - 63);
        extw[j] = scale * (1.f - __expf(-(fr2 + d * d) * INV2S2));
    }
}

// per-lane register table e[dm][r], dm = mi-ni+3
__device__ __forceinline__ void load_etab(const float* extw_wave, int quad, int l15,
                                          float (&e)[7][4]) {
    const float* p = extw_wave + 63 + quad * 4 - l15;
#pragma unroll
    for (int dm = 0; dm < 7; ++dm)
#pragma unroll
        for (int r = 0; r < 4; ++r) e[dm][r] = p[(dm - 3) * 16 + r];
}

// ---------------- pass B: rowsum partials + last-block recip finisher ----------------
// rpart[((b*32 + strip)*32 + slot)*128 + j]; strip s <- row-sums of tiles (s,nt) at
// slot nt, col-sums of tiles (mt,s) at slot mt. 32 writers/strip; 32nd finishes.
__global__ __launch_bounds__(256) void corr_rowsum(const bf16* __restrict__ xnT,
                                                   const float* __restrict__ alpha_p,
                                                   float* __restrict__ rpart,
                                                   float* __restrict__ ism,
                                                   float* __restrict__ lsm,
                                                   int* __restrict__ cnt) {
    __shared__ __align__(16) bf16 SH[16384];  // 32KB: As[2][4096] | Bs[2][4096]
    __shared__ int fin0, fin1;
    bf16* As = SH;
    bf16* Bs = SH + 8192;
    int tid = threadIdx.x;
    int lin = blockIdx.x;
    int xcd = lin & 7;
    int b = xcd >> 1;
    int t = ((lin >> 3) << 1) + (xcd & 1);  // [0, 528)
    int mt, nt;
    decode_tri(t, mt, nt);
    int mbase = mt * 128, nbase = nt * 128;
    int wave = tid >> 6, lane = tid & 63;
    int wm = wave >> 1, wn = wave & 1, l15 = lane & 15, quad = lane >> 4;
    int rowi = (mbase + wm * 64) >> 6;
    int coli = (nbase + wn * 64) >> 6;
    int adr = rowi - coli; if (adr < 0) adr = -adr;
    float alpha = alpha_p[0];

    f32x4 acc[4][4];
    gemm_tile(xnT + ((size_t)b << 20), mbase, nbase, As, Bs, acc);

    float* F = (float*)SH;
    float* ext  = F;              // [4][128] wave-private (dead As-buf0)
    float* rbuf = F + 512;        // [2][128]
    float* cbuf = F + 768;        // [2][128]
    build_ext(ext + wave * 128, lane, adr, alpha);
    float e[7][4];
    load_etab(ext + wave * 128, quad, l15, e);

    float colpart[4] = {0.f, 0.f, 0.f, 0.f};
#pragma unroll
    for (int mi = 0; mi < 4; ++mi) {
#pragma unroll
        for (int r = 0; r < 4; ++r) {
            float ssum = 0.f;
#pragma unroll
            for (int ni = 0; ni < 4; ++ni) {
                float s = e[mi - ni + 3][r] * acc[mi][ni][r];
                float ev = __expf(s);
                ssum += ev;
                colpart[ni] += ev;
            }
            ssum += __shfl_xor(ssum, 1);
            ssum += __shfl_xor(ssum, 2);
            ssum += __shfl_xor(ssum, 4);
            ssum += __shfl_xor(ssum, 8);
            if (l15 == 0) rbuf[wn * 128 + wm * 64 + mi * 16 + quad * 4 + r] = ssum;
        }
    }
#pragma unroll
    for (int ni = 0; ni < 4; ++ni) {
        float c = colpart[ni];
        c += __shfl_xor(c, 16);
        c += __shfl_xor(c, 32);
        if (quad == 0) cbuf[wm * 128 + wn * 64 + ni * 16 + l15] = c;
    }
    __syncthreads();
    if (tid < 128) {
        rpart[(size_t)((b * 32 + mt) * 32 + nt) * 128 + tid] = rbuf[tid] + rbuf[128 + tid];
    } else if (mt != nt) {
        int j = tid - 128;
        rpart[(size_t)((b * 32 + nt) * 32 + mt) * 128 + j] = cbuf[j] + cbuf[128 + j];
    }
    // ---- finisher: 32nd slot-writer of a strip computes that strip's recip ----
    __syncthreads();  // all slot stores complete (vmcnt(0) before s_barrier)
    if (tid == 0) {
        __threadfence();  // release: write back this block's rpart lines
        int oa = __hip_atomic_fetch_add(&cnt[b * 32 + mt], 1, __ATOMIC_RELAXED,
                                        __HIP_MEMORY_SCOPE_AGENT);
        int f0 = (oa == 31);
        int f1 = 0;
        if (mt != nt) {
            int ob = __hip_atomic_fetch_add(&cnt[b * 32 + nt], 1, __ATOMIC_RELAXED,
                                            __HIP_MEMORY_SCOPE_AGENT);
            f1 = (ob == 31);
        }
        if (f0 | f1) __threadfence();  // acquire: fresh reads of others' slots
        fin0 = f0;
        fin1 = f1;
    }
    __syncthreads();
    if (tid < 128) {
        if (fin0) {  // strip mt: identical loop to old corr_recip
            int i = (b << 12) + mt * 128 + tid;
            const float* base = rpart + (size_t)((b * 32 + mt) * 32) * 128 + tid;
            float sum = 0.f;
#pragma unroll
            for (int sl = 0; sl < 32; ++sl) sum += base[sl * 128];
            ism[i] = 1.0f / sum;
            lsm[i] = -__logf(sum);
        }
        if (fin1) {  // strip nt
            int i = (b << 12) + nt * 128 + tid;
            const float* base = rpart + (size_t)((b * 32 + nt) * 32) * 128 + tid;
            float sum = 0.f;
#pragma unroll
            for (int sl = 0; sl < 32; ++sl) sum += base[sl * 128];
            ism[i] = 1.0f / sum;
            lsm[i] = -__logf(sum);
        }
    }
}

// ---------------- pass C: triangular dual-direction top-3 + last-block merge finisher ----
// wtop[((b*32+strip)*32+slot)*128+j][3]; strip nt slot mt from col-dir, strip mt
// slot nt from row-dir (off-diag). 32 writers/strip; 32nd merges + writes out.
__global__ __launch_bounds__(256) void corr_topk(const bf16* __restrict__ xnT,
                                                 const float* __restrict__ alpha_p,
                                                 const float* __restrict__ lsm,
                                                 const float* __restrict__ ism,
                                                 float* __restrict__ wtop,
                                                 float* __restrict__ out,
                                                 int* __restrict__ cnt) {
    __shared__ __align__(16) bf16 SH[16384];  // 32KB
    __shared__ int fin0, fin1;
    bf16* As = SH;
    bf16* Bs = SH + 8192;
    int tid = threadIdx.x;
    int lin = blockIdx.x;
    int xcd = lin & 7;
    int b = xcd >> 1;
    int t = ((lin >> 3) << 1) + (xcd & 1);  // [0, 528)
    int mt, nt;
    decode_tri(t, mt, nt);
    int mbase = mt * 128, nbase = nt * 128;
    int wave = tid >> 6, lane = tid & 63;
    int wm = wave >> 1, wn = wave & 1, l15 = lane & 15, quad = lane >> 4;
    int rowi = (mbase + wm * 64) >> 6;
    int coli = (nbase + wn * 64) >> 6;
    int adr = rowi - coli; if (adr < 0) adr = -adr;
    float a2 = 2.0f * alpha_p[0];

    f32x4 acc[4][4];
    gemm_tile(xnT + ((size_t)b << 20), mbase, nbase, As, Bs, acc);

    float* F = (float*)SH;
    float* ext  = F;              // [4][128]            floats 0..511 (dead buf0)
    float* mbuf = F + 512;        // [2][128][3]         floats 512..1279
    float* rtop = F + 1280;       // [128][51]: odd stride -> full bank spread
    build_ext(ext + wave * 128, lane, adr, a2);
    float e[7][4];
    load_etab(ext + wave * 128, quad, l15, e);

    float lr[4][4];
#pragma unroll
    for (int mi = 0; mi < 4; ++mi)
#pragma unroll
        for (int r = 0; r < 4; ++r)
            lr[mi][r] = lsm[(b << 12) + mbase + wm * 64 + mi * 16 + quad * 4 + r];
    float lc[4];
#pragma unroll
    for (int ni = 0; ni < 4; ++ni)
        lc[ni] = lsm[(b << 12) + nbase + wn * 64 + ni * 16 + l15];

    // ---- column direction: top3 over rows for each tile column ----
#pragma unroll
    for (int ni = 0; ni < 4; ++ni) {
        float t0 = NEGINF, t1 = NEGINF, t2 = NEGINF;
#pragma unroll
        for (int mi = 0; mi < 4; ++mi) {
#pragma unroll
            for (int r = 0; r < 4; ++r) {
                float key = fmaf(e[mi - ni + 3][r], acc[mi][ni][r], lr[mi][r]);
                ins3(key, t0, t1, t2);
            }
        }
#pragma unroll
        for (int d = 16; d <= 32; d <<= 1) {
            float s0 = __shfl_xor(t0, d);
            float s1 = __shfl_xor(t1, d);
            float s2 = __shfl_xor(t2, d);
            ins3(s0, t0, t1, t2);
            ins3(s1, t0, t1, t2);
            ins3(s2, t0, t1, t2);
        }
        if (quad == 0) {
            int cl = wn * 64 + ni * 16 + l15;
            mbuf[(wm * 128 + cl) * 3 + 0] = t0;
            mbuf[(wm * 128 + cl) * 3 + 1] = t1;
            mbuf[(wm * 128 + cl) * 3 + 2] = t2;
        }
    }
    __syncthreads();  // GEMM LDS reads done -> rtop region reusable

    // ---- row direction (xc[c,n]=xc[n,c]): top3 over cols for each tile row ----
    if (mt != nt) {
#pragma unroll
        for (int mi = 0; mi < 4; ++mi) {
#pragma unroll
            for (int r = 0; r < 4; ++r) {
                float u0 = NEGINF, u1 = NEGINF, u2 = NEGINF;
#pragma unroll
                for (int ni = 0; ni < 4; ++ni) {
                    float key = fmaf(e[mi - ni + 3][r], acc[mi][ni][r], lc[ni]);
                    ins3(key, u0, u1, u2);
                }
                {
                    float s0 = __shfl_xor(u0, 8);
                    float s1 = __shfl_xor(u1, 8);
                    float s2 = __shfl_xor(u2, 8);
                    ins3(s0, u0, u1, u2);
                    ins3(s1, u0, u1, u2);
                    ins3(s2, u0, u1, u2);
                }
                if (l15 < 8) {
                    int row = wm * 64 + mi * 16 + quad * 4 + r;
                    int slot = wn * 8 + l15;
                    float* q = rtop + row * 51 + slot * 3;
                    q[0] = u0; q[1] = u1; q[2] = u2;
                }
            }
        }
    }
    __syncthreads();
    if (tid < 128) {
        // column-direction: strip nt, slot mt, column nbase+tid
        float t0 = mbuf[tid * 3], t1 = mbuf[tid * 3 + 1], t2 = mbuf[tid * 3 + 2];
        ins3(mbuf[(128 + tid) * 3 + 0], t0, t1, t2);
        ins3(mbuf[(128 + tid) * 3 + 1], t0, t1, t2);
        ins3(mbuf[(128 + tid) * 3 + 2], t0, t1, t2);
        size_t o = ((size_t)((b * 32 + nt) * 32 + mt) * 128 + tid) * 3;
        wtop[o] = t0;
        wtop[o + 1] = t1;
        wtop[o + 2] = t2;
        if (mt != nt) {
            // row-direction: strip mt, slot nt, column mbase+tid
            float v0 = NEGINF, v1 = NEGINF, v2 = NEGINF;
            const float* q = rtop + tid * 51;
#pragma unroll
            for (int sl = 0; sl < 16; ++sl) {
                ins3(q[sl * 3 + 0], v0, v1, v2);
                ins3(q[sl * 3 + 1], v0, v1, v2);
                ins3(q[sl * 3 + 2], v0, v1, v2);
            }
            size_t o2 = ((size_t)((b * 32 + mt) * 32 + nt) * 128 + tid) * 3;
            wtop[o2] = v0;
            wtop[o2 + 1] = v1;
            wtop[o2 + 2] = v2;
        }
    }
    // ---- finisher: 32nd slot-writer of a strip merges it and writes out ----
    __syncthreads();  // all wtop stores complete
    if (tid == 0) {
        __threadfence();  // release
        int oa = __hip_atomic_fetch_add(&cnt[b * 32 + nt], 1, __ATOMIC_RELAXED,
                                        __HIP_MEMORY_SCOPE_AGENT);
        int f0 = (oa == 31);
        int f1 = 0;
        if (mt != nt) {
            int ob = __hip_atomic_fetch_add(&cnt[b * 32 + mt], 1, __ATOMIC_RELAXED,
                                            __HIP_MEMORY_SCOPE_AGENT);
            f1 = (ob == 31);
        }
        if (f0 | f1) __threadfence();  // acquire
        fin0 = f0;
        fin1 = f1;
    }
    __syncthreads();
    if (tid < 128) {
        for (int pass = 0; pass < 2; ++pass) {
            int s = pass == 0 ? nt : mt;
            int go = pass == 0 ? fin0 : fin1;
            if (!go) continue;
            // identical loop to old corr_merge for column idx
            int idx = (b << 12) + s * 128 + tid;
            const float* base = wtop + ((size_t)((b * 32 + s) * 32) * 128 + tid) * 3;
            float t0 = NEGINF, t1 = NEGINF, t2 = NEGINF;
            for (int sl = 0; sl < 32; ++sl) {
                const float* q = base + (size_t)sl * 128 * 3;
                ins3(q[0], t0, t1, t2);
                ins3(q[1], t0, t1, t2);
                ins3(q[2], t0, t1, t2);
            }
            float ismc = ism[idx];
            int col = s * 128 + tid;
            out[((b * 3 + 0) << 12) + col] = __expf(t0) * ismc;
            out[((b * 3 + 1) << 12) + col] = __expf(t1) * ismc;
            out[((b * 3 + 2) << 12) + col] = __expf(t2) * ismc;
        }
    }
}

extern "C" void kernel_launch(void* const* d_in, const int* in_sizes, int n_in,
                              void* d_out, int out_size, void* d_ws, size_t ws_size,
                              hipStream_t stream) {
    const float* x = (const float*)d_in[0];
    const float* alpha = (const float*)d_in[1];
    float* out = (float*)d_out;
    char* ws = (char*)d_ws;
    bf16* xnT = (bf16*)ws;                                    // 8 MB
    float* ism = (float*)(ws + (8u << 20));                   // 64 KB
    float* lsm = (float*)(ws + (8u << 20) + (64u << 10));     // 64 KB
    // rpart (2 MB, lifetime = rowsum kernel) aliases wtop (6 MB, topk kernel).
    float* rpart = (float*)(ws + (8u << 20) + (128u << 10));
    float* wtop  = (float*)(ws + (8u << 20) + (128u << 10));
    // strip counters after wtop: cntA 128 ints (rowsum), cntB 128 ints (topk).
    int* cntA = (int*)(ws + (8u << 20) + (128u << 10) + (6u << 20));
    int* cntB = cntA + 128;

    hipMemsetAsync(cntA, 0, 256 * sizeof(int), stream);
    corr_norm<<<256, 256, 0, stream>>>(x, xnT);
    corr_rowsum<<<NTILE * 4, 256, 0, stream>>>(xnT, alpha, rpart, ism, lsm, cntA);
    corr_topk<<<NTILE * 4, 256, 0, stream>>>(xnT, alpha, lsm, ism, wtop, out, cntB);
}

// Round 14
// 140.460 us; speedup vs baseline: 3.2755x; 1.8545x over previous
//
#include <hip/hip_runtime.h>
#include <hip/hip_bf16.h>

// Corr: B=4, C=256, H=W=64, HW=4096, TOPK=3, rat_s=0.05 -> sigma=3.2, 2*sigma^2=20.48
// s[m,n] = alpha * (1 - exp(-(dr^2+dc^2)/20.48)) * <xn_m, xn_n>  (symmetric)
// xc[m,n] = exp(2 s[m,n]) / (sm[m] sm[n]),  sm[m] = sum_n exp(s[m,n])
// out[b,k,col] = top-3 over m of xc[m,col]
//
// R1..R9 (proven, 155us): XCD<->batch binding, log-domain top-k, non-atomic
//   partials, k-slot swizzle, triangular dual-direction topk, __syncthreads
//   K-loop, odd-stride rtop, LDS-transposed norm.
// BANNED (measured): raw vmcnt barriers w/ LDS-DMA (R7), cooperative launch
//   (R10), spin barriers (R11), per-block device fences (R12) — the last two
//   poison the XCD L2 via coherence invalidations.
// R13: single-GEMM pipeline. rowsum stores s2 = 2*alpha*(1-g)*acc as fp16
//   tiles (69MB, coalesced); topk's GEMM recompute is replaced by a streaming
//   selector (no MFMA, no staging, no K-loop barriers). ism/lsm bit-identical
//   (fp32 path untouched); fp16 s2 adds ~2e-9 abs. Falls back to exact R9
//   pipeline if ws_size < 84MB.

#define HW 4096
#define CDIM 256
#define INV2S2 0.048828125f  // 1/20.48
#define NEGINF -1e30f
#define NTILE 528

typedef __bf16 bf16;
typedef _Float16 f16;
typedef __attribute__((ext_vector_type(8))) __bf16 bf16x8;
typedef __attribute__((ext_vector_type(4))) _Float16 f16x4;
typedef __attribute__((ext_vector_type(4))) float f32x4;

#define GAS __attribute__((address_space(1)))
#define LAS __attribute__((address_space(3)))

__device__ __forceinline__ void ins3(float v, float& t0, float& t1, float& t2) {
    // maintains t0>=t1>=t2; exact top-3 insert in 3 VALU ops (v_max + 2x v_med3)
    float n0 = fmaxf(t0, v);
    float n1 = __builtin_amdgcn_fmed3f(t0, t1, v);
    float n2 = __builtin_amdgcn_fmed3f(t1, t2, v);
    t0 = n0; t1 = n1; t2 = n2;
}

// triangular decode: t = mt*(mt+1)/2 + nt, nt <= mt
__device__ __forceinline__ void decode_tri(int t, int& mt, int& nt) {
    int m = (int)((sqrtf(8.f * (float)t + 1.f) - 1.f) * 0.5f);
    while ((m + 1) * (m + 2) / 2 <= t) ++m;
    while (m * (m + 1) / 2 > t) --m;
    mt = m;
    nt = t - m * (m + 1) / 2;
}

// ---------------- normalize + transpose to bf16 xnT[b][pixel][channel] ----------------
__global__ __launch_bounds__(256) void corr_norm(const float* __restrict__ x,
                                                 bf16* __restrict__ xnT) {
    __shared__ float red[4][64];
    __shared__ float invn[64];
    __shared__ __align__(16) bf16 T[64][264];  // 264 = 256 + 8 pad
    int tid = threadIdx.x;
    int pl = tid & 63, cg = tid >> 6;
    int P0 = blockIdx.x * 64;
    int P = P0 + pl;
    int b = P >> 12;
    int pix = P & 4095;
    const float* xb = x + ((size_t)(b * CDIM + cg * 64) << 12) + pix;
    float v[64];
    float ss = 0.f;
#pragma unroll
    for (int j = 0; j < 64; ++j) {
        v[j] = xb[(size_t)j << 12];
        ss += v[j] * v[j];
    }
    red[cg][pl] = ss;
    __syncthreads();
    if (tid < 64) {
        float s = red[0][tid] + red[1][tid] + red[2][tid] + red[3][tid];
        invn[tid] = 1.0f / fmaxf(sqrtf(s), 1e-12f);
    }
    __syncthreads();
    float inv = invn[pl];
#pragma unroll
    for (int j0 = 0; j0 < 64; j0 += 8) {
        bf16x8 pk;
#pragma unroll
        for (int j = 0; j < 8; ++j) pk[j] = (bf16)(v[j0 + j] * inv);
        *(bf16x8*)(&T[pl][cg * 64 + j0]) = pk;
    }
    __syncthreads();
#pragma unroll
    for (int it = 0; it < 8; ++it) {
        int p = it * 8 + (tid >> 5);
        int k = tid & 31;
        bf16x8 val = *(const bf16x8*)(&T[p][k * 8]);
        *(bf16x8*)(xnT + (size_t)(P0 + p) * CDIM + k * 8) = val;
    }
}

// ---------------- GEMM tile core: 128x128, K=256, dbuf single-barrier, k-slot swizzle ----
__device__ __forceinline__ void gemm_tile(const bf16* __restrict__ xb, int mbase, int nbase,
                                          bf16* As, bf16* Bs, f32x4 (&acc)[4][4]) {
    const int tid = threadIdx.x;
    const int wave = tid >> 6;
    const int lane = tid & 63;
    const int wm = wave >> 1, wn = wave & 1;
    const int l15 = lane & 15, quad = lane >> 4;
#pragma unroll
    for (int mi = 0; mi < 4; ++mi)
#pragma unroll
        for (int ni = 0; ni < 4; ++ni) acc[mi][ni] = (f32x4)0.f;

    auto issue = [&](int kk, int buf) {
#pragma unroll
        for (int r = 0; r < 2; ++r) {
            int idx = r * 256 + tid;
            int prow = idx >> 2;
            int sub = ((idx & 3) - (prow >> 1)) & 3;  // swizzled k-group
            const bf16* gA = xb + ((size_t)(mbase + prow) << 8) + kk * 32 + (sub << 3);
            const bf16* gB = xb + ((size_t)(nbase + prow) << 8) + kk * 32 + (sub << 3);
            bf16* lA = As + buf * 4096 + ((r * 4 + wave) << 9);
            bf16* lB = Bs + buf * 4096 + ((r * 4 + wave) << 9);
            __builtin_amdgcn_global_load_lds((const GAS void*)gA, (LAS void*)lA, 16, 0, 0);
            __builtin_amdgcn_global_load_lds((const GAS void*)gB, (LAS void*)lB, 16, 0, 0);
        }
    };
    issue(0, 0);
    const int rslot = ((quad + (l15 >> 1)) & 3) * 8;
#pragma unroll
    for (int kk = 0; kk < 8; ++kk) {
        __syncthreads();
        if (kk < 7) issue(kk + 1, (kk + 1) & 1);
        int buf = kk & 1;
        bf16x8 af[4], bfr[4];
#pragma unroll
        for (int i = 0; i < 4; ++i) {
            af[i]  = *(const bf16x8*)(As + buf * 4096 + (wm * 64 + i * 16 + l15) * 32 + rslot);
            bfr[i] = *(const bf16x8*)(Bs + buf * 4096 + (wn * 64 + i * 16 + l15) * 32 + rslot);
        }
#pragma unroll
        for (int mi = 0; mi < 4; ++mi)
#pragma unroll
            for (int ni = 0; ni < 4; ++ni)
                acc[mi][ni] = __builtin_amdgcn_mfma_f32_16x16x32_bf16(af[mi], bfr[ni],
                                                                      acc[mi][ni], 0, 0, 0);
    }
}

// extw[j] = scale*(1 - exp(-(adr^2+(j-63)^2)/20.48)), j in [0,128) — wave-private
__device__ __forceinline__ void build_ext(float* extw, int lane, int adr, float scale) {
    float fr2 = (float)(adr * adr);
#pragma unroll
    for (int h = 0; h < 2; ++h) {
        int j = lane + h * 64;
        float d = (float)(j - 63);
        extw[j] = scale * (1.f - __expf(-(fr2 + d * d) * INV2S2));
    }
}

// per-lane register table e[dm][r], dm = mi-ni+3
__device__ __forceinline__ void load_etab(const float* extw_wave, int quad, int l15,
                                          float (&e)[7][4]) {
    const float* p = extw_wave + 63 + quad * 4 - l15;
#pragma unroll
    for (int dm = 0; dm < 7; ++dm)
#pragma unroll
        for (int r = 0; r < 4; ++r) e[dm][r] = p[(dm - 3) * 16 + r];
}

// ---------------- pass B: rowsum partials (+ optional fp16 s2 store) ----------------
__global__ __launch_bounds__(256) void corr_rowsum(const bf16* __restrict__ xnT,
                                                   const float* __restrict__ alpha_p,
                                                   float* __restrict__ rpart,
                                                   f16* __restrict__ sbuf,
                                                   int store_s2) {
    __shared__ __align__(16) bf16 SH[16384];
    bf16* As = SH;
    bf16* Bs = SH + 8192;
    int tid = threadIdx.x;
    int lin = blockIdx.x;
    int xcd = lin & 7;
    int b = xcd >> 1;
    int t = ((lin >> 3) << 1) + (xcd & 1);  // [0, 528)
    int mt, nt;
    decode_tri(t, mt, nt);
    int mbase = mt * 128, nbase = nt * 128;
    int wave = tid >> 6, lane = tid & 63;
    int wm = wave >> 1, wn = wave & 1, l15 = lane & 15, quad = lane >> 4;
    int rowi = (mbase + wm * 64) >> 6;
    int coli = (nbase + wn * 64) >> 6;
    int adr = rowi - coli; if (adr < 0) adr = -adr;
    float alpha = alpha_p[0];

    f32x4 acc[4][4];
    gemm_tile(xnT + ((size_t)b << 20), mbase, nbase, As, Bs, acc);

    float* F = (float*)SH;
    float* ext  = F;              // [4][128] wave-private (dead As-buf0)
    float* rbuf = F + 512;        // [2][128]
    float* cbuf = F + 768;        // [2][128]
    build_ext(ext + wave * 128, lane, adr, alpha);
    float e[7][4];
    load_etab(ext + wave * 128, quad, l15, e);

    const size_t tb = (size_t)(b * NTILE + t) * 16384;
    float colpart[4] = {0.f, 0.f, 0.f, 0.f};
#pragma unroll
    for (int mi = 0; mi < 4; ++mi) {
#pragma unroll
        for (int r = 0; r < 4; ++r) {
            float ssum = 0.f;
            float sv[4];
#pragma unroll
            for (int ni = 0; ni < 4; ++ni) {
                float s = e[mi - ni + 3][r] * acc[mi][ni][r];
                sv[ni] = s;
                float ev = __expf(s);
                ssum += ev;
                colpart[ni] += ev;
            }
            if (store_s2) {
                // s2 region (mi,r): 1024 halfs; lane writes 8B coalesced
                f16x4 pk;
#pragma unroll
                for (int ni = 0; ni < 4; ++ni) pk[ni] = (f16)(sv[ni] + sv[ni]);
                *(f16x4*)(sbuf + tb + (mi * 4 + r) * 1024 + tid * 4) = pk;
            }
            ssum += __shfl_xor(ssum, 1);
            ssum += __shfl_xor(ssum, 2);
            ssum += __shfl_xor(ssum, 4);
            ssum += __shfl_xor(ssum, 8);
            if (l15 == 0) rbuf[wn * 128 + wm * 64 + mi * 16 + quad * 4 + r] = ssum;
        }
    }
#pragma unroll
    for (int ni = 0; ni < 4; ++ni) {
        float c = colpart[ni];
        c += __shfl_xor(c, 16);
        c += __shfl_xor(c, 32);
        if (quad == 0) cbuf[wm * 128 + wn * 64 + ni * 16 + l15] = c;
    }
    __syncthreads();
    if (tid < 128) {
        rpart[(size_t)((b * 32 + mt) * 32 + nt) * 128 + tid] = rbuf[tid] + rbuf[128 + tid];
    } else if (mt != nt) {
        int j = tid - 128;
        rpart[(size_t)((b * 32 + nt) * 32 + mt) * 128 + j] = cbuf[j] + cbuf[128 + j];
    }
}

// ---------------- slot-reduce + reciprocal + negative log ----------------
__global__ __launch_bounds__(256) void corr_recip(const float* __restrict__ rpart,
                                                  float* __restrict__ ism,
                                                  float* __restrict__ lsm) {
    int i = blockIdx.x * 256 + threadIdx.x;
    if (i >= 4 * HW) return;
    int b = i >> 12, gr = i & 4095, s = gr >> 7, j = gr & 127;
    const float* base = rpart + (size_t)((b * 32 + s) * 32) * 128 + j;
    float sum = 0.f;
#pragma unroll
    for (int sl = 0; sl < 32; ++sl) sum += base[sl * 128];
    ism[i] = 1.0f / sum;
    lsm[i] = -__logf(sum);
}

// ================= shared epilogue for both topk variants =================
// keys[(mi*4+r)*4+ni] = 2s + per-dir log term; does dual-direction select+store.
__device__ __forceinline__ void topk_epilogue(int b, int mt, int nt,
                                              const float (&s2f)[16][4],
                                              const float (&lr)[4][4], const float (&lc)[4],
                                              float* mbuf, float* rtop,
                                              float* __restrict__ wtop,
                                              int tid, int wm, int wn, int l15, int quad) {
    // ---- column direction: top3 over rows for each tile column ----
#pragma unroll
    for (int ni = 0; ni < 4; ++ni) {
        float t0 = NEGINF, t1 = NEGINF, t2 = NEGINF;
#pragma unroll
        for (int mi = 0; mi < 4; ++mi) {
#pragma unroll
            for (int r = 0; r < 4; ++r) {
                float key = s2f[mi * 4 + r][ni] + lr[mi][r];
                ins3(key, t0, t1, t2);
            }
        }
#pragma unroll
        for (int d = 16; d <= 32; d <<= 1) {
            float s0 = __shfl_xor(t0, d);
            float s1 = __shfl_xor(t1, d);
            float s2 = __shfl_xor(t2, d);
            ins3(s0, t0, t1, t2);
            ins3(s1, t0, t1, t2);
            ins3(s2, t0, t1, t2);
        }
        if (quad == 0) {
            int cl = wn * 64 + ni * 16 + l15;
            mbuf[(wm * 128 + cl) * 3 + 0] = t0;
            mbuf[(wm * 128 + cl) * 3 + 1] = t1;
            mbuf[(wm * 128 + cl) * 3 + 2] = t2;
        }
    }
    __syncthreads();
    // ---- row direction (xc[c,n]=xc[n,c]): top3 over cols for each tile row ----
    if (mt != nt) {
#pragma unroll
        for (int mi = 0; mi < 4; ++mi) {
#pragma unroll
            for (int r = 0; r < 4; ++r) {
                float u0 = NEGINF, u1 = NEGINF, u2 = NEGINF;
#pragma unroll
                for (int ni = 0; ni < 4; ++ni) {
                    float key = s2f[mi * 4 + r][ni] + lc[ni];
                    ins3(key, u0, u1, u2);
                }
                {
                    float s0 = __shfl_xor(u0, 8);
                    float s1 = __shfl_xor(u1, 8);
                    float s2 = __shfl_xor(u2, 8);
                    ins3(s0, u0, u1, u2);
                    ins3(s1, u0, u1, u2);
                    ins3(s2, u0, u1, u2);
                }
                if (l15 < 8) {
                    int row = wm * 64 + mi * 16 + quad * 4 + r;
                    int slot = wn * 8 + l15;
                    float* q = rtop + row * 51 + slot * 3;
                    q[0] = u0; q[1] = u1; q[2] = u2;
                }
            }
        }
    }
    __syncthreads();
    if (tid < 128) {
        float t0 = mbuf[tid * 3], t1 = mbuf[tid * 3 + 1], t2 = mbuf[tid * 3 + 2];
        ins3(mbuf[(128 + tid) * 3 + 0], t0, t1, t2);
        ins3(mbuf[(128 + tid) * 3 + 1], t0, t1, t2);
        ins3(mbuf[(128 + tid) * 3 + 2], t0, t1, t2);
        size_t o = ((size_t)((b * 32 + nt) * 32 + mt) * 128 + tid) * 3;
        wtop[o] = t0;
        wtop[o + 1] = t1;
        wtop[o + 2] = t2;
        if (mt != nt) {
            float v0 = NEGINF, v1 = NEGINF, v2 = NEGINF;
            const float* q = rtop + tid * 51;
#pragma unroll
            for (int sl = 0; sl < 16; ++sl) {
                ins3(q[sl * 3 + 0], v0, v1, v2);
                ins3(q[sl * 3 + 1], v0, v1, v2);
                ins3(q[sl * 3 + 2], v0, v1, v2);
            }
            size_t o2 = ((size_t)((b * 32 + mt) * 32 + nt) * 128 + tid) * 3;
            wtop[o2] = v0;
            wtop[o2 + 1] = v1;
            wtop[o2 + 2] = v2;
        }
    }
}

// ---------------- pass C (fast): streaming selector over stored fp16 s2 ----------------
__global__ __launch_bounds__(256) void corr_topsel(const f16* __restrict__ sbuf,
                                                   const float* __restrict__ lsm,
                                                   float* __restrict__ wtop) {
    __shared__ float FS[7296];  // mbuf 768 | rtop 128*51
    float* mbuf = FS;
    float* rtop = FS + 768;
    int tid = threadIdx.x;
    int lin = blockIdx.x;
    int xcd = lin & 7;
    int b = xcd >> 1;
    int t = ((lin >> 3) << 1) + (xcd & 1);
    int mt, nt;
    decode_tri(t, mt, nt);
    int mbase = mt * 128, nbase = nt * 128;
    int wave = tid >> 6, lane = tid & 63;
    int wm = wave >> 1, wn = wave & 1, l15 = lane & 15, quad = lane >> 4;

    const size_t tb = (size_t)(b * NTILE + t) * 16384;
    float s2f[16][4];
#pragma unroll
    for (int k = 0; k < 16; ++k) {
        f16x4 hv = *(const f16x4*)(sbuf + tb + k * 1024 + tid * 4);
#pragma unroll
        for (int ni = 0; ni < 4; ++ni) s2f[k][ni] = (float)hv[ni];
    }
    float lr[4][4];
#pragma unroll
    for (int mi = 0; mi < 4; ++mi)
#pragma unroll
        for (int r = 0; r < 4; ++r)
            lr[mi][r] = lsm[(b << 12) + mbase + wm * 64 + mi * 16 + quad * 4 + r];
    float lc[4];
#pragma unroll
    for (int ni = 0; ni < 4; ++ni)
        lc[ni] = lsm[(b << 12) + nbase + wn * 64 + ni * 16 + l15];

    topk_epilogue(b, mt, nt, s2f, lr, lc, mbuf, rtop, wtop, tid, wm, wn, l15, quad);
}

// ---------------- pass C (fallback): R9 full-GEMM topk ----------------
__global__ __launch_bounds__(256) void corr_topk(const bf16* __restrict__ xnT,
                                                 const float* __restrict__ alpha_p,
                                                 const float* __restrict__ lsm,
                                                 float* __restrict__ wtop) {
    __shared__ __align__(16) bf16 SH[16384];
    bf16* As = SH;
    bf16* Bs = SH + 8192;
    int tid = threadIdx.x;
    int lin = blockIdx.x;
    int xcd = lin & 7;
    int b = xcd >> 1;
    int t = ((lin >> 3) << 1) + (xcd & 1);
    int mt, nt;
    decode_tri(t, mt, nt);
    int mbase = mt * 128, nbase = nt * 128;
    int wave = tid >> 6, lane = tid & 63;
    int wm = wave >> 1, wn = wave & 1, l15 = lane & 15, quad = lane >> 4;
    int rowi = (mbase + wm * 64) >> 6;
    int coli = (nbase + wn * 64) >> 6;
    int adr = rowi - coli; if (adr < 0) adr = -adr;
    float a2 = 2.0f * alpha_p[0];

    f32x4 acc[4][4];
    gemm_tile(xnT + ((size_t)b << 20), mbase, nbase, As, Bs, acc);

    float* F = (float*)SH;
    float* ext  = F;
    float* mbuf = F + 512;
    float* rtop = F + 1280;
    build_ext(ext + wave * 128, lane, adr, a2);
    float e[7][4];
    load_etab(ext + wave * 128, quad, l15, e);

    float s2f[16][4];
#pragma unroll
    for (int mi = 0; mi < 4; ++mi)
#pragma unroll
        for (int r = 0; r < 4; ++r)
#pragma unroll
            for (int ni = 0; ni < 4; ++ni)
                s2f[mi * 4 + r][ni] = e[mi - ni + 3][r] * acc[mi][ni][r];
    float lr[4][4];
#pragma unroll
    for (int mi = 0; mi < 4; ++mi)
#pragma unroll
        for (int r = 0; r < 4; ++r)
            lr[mi][r] = lsm[(b << 12) + mbase + wm * 64 + mi * 16 + quad * 4 + r];
    float lc[4];
#pragma unroll
    for (int ni = 0; ni < 4; ++ni)
        lc[ni] = lsm[(b << 12) + nbase + wn * 64 + ni * 16 + l15];

    __syncthreads();  // GEMM LDS reads done; mbuf/rtop reuse safe
    topk_epilogue(b, mt, nt, s2f, lr, lc, mbuf, rtop, wtop, tid, wm, wn, l15, quad);
}

// ---------------- final merge of 32 slot-partials per column; exp + column scale ----------------
__global__ __launch_bounds__(256) void corr_merge(const float* __restrict__ wtop,
                                                  const float* __restrict__ ism,
                                                  float* __restrict__ out) {
    int idx = blockIdx.x * 256 + threadIdx.x;
    if (idx >= 4 * HW) return;
    int b = idx >> 12, col = idx & 4095;
    int strip = col >> 7, j = col & 127;
    const float* base = wtop + ((size_t)((b * 32 + strip) * 32) * 128 + j) * 3;
    float t0 = NEGINF, t1 = NEGINF, t2 = NEGINF;
    for (int sl = 0; sl < 32; ++sl) {
        const float* q = base + (size_t)sl * 128 * 3;
        ins3(q[0], t0, t1, t2);
        ins3(q[1], t0, t1, t2);
        ins3(q[2], t0, t1, t2);
    }
    float ismc = ism[idx];
    out[((b * 3 + 0) << 12) + col] = __expf(t0) * ismc;
    out[((b * 3 + 1) << 12) + col] = __expf(t1) * ismc;
    out[((b * 3 + 2) << 12) + col] = __expf(t2) * ismc;
}

extern "C" void kernel_launch(void* const* d_in, const int* in_sizes, int n_in,
                              void* d_out, int out_size, void* d_ws, size_t ws_size,
                              hipStream_t stream) {
    const float* x = (const float*)d_in[0];
    const float* alpha = (const float*)d_in[1];
    float* out = (float*)d_out;
    char* ws = (char*)d_ws;
    bf16* xnT = (bf16*)ws;                                    // 8 MB
    float* ism = (float*)(ws + (8u << 20));                   // 64 KB
    float* lsm = (float*)(ws + (8u << 20) + (64u << 10));     // 64 KB
    float* rpart = (float*)(ws + (8u << 20) + (128u << 10));  // 2 MB (aliases wtop)
    float* wtop  = (float*)(ws + (8u << 20) + (128u << 10));  // 6 MB
    f16* sbuf = (f16*)(ws + (8u << 20) + (128u << 10) + (6u << 20));
    size_t need = (8u << 20) + (128u << 10) + (6u << 20) + (size_t)4 * NTILE * 16384 * 2;
    int fast = (ws_size >= need);

    corr_norm<<<256, 256, 0, stream>>>(x, xnT);
    corr_rowsum<<<NTILE * 4, 256, 0, stream>>>(xnT, alpha, rpart, sbuf, fast);
    corr_recip<<<64, 256, 0, stream>>>(rpart, ism, lsm);
    if (fast)
        corr_topsel<<<NTILE * 4, 256, 0, stream>>>(sbuf, lsm, wtop);
    else
        corr_topk<<<NTILE * 4, 256, 0, stream>>>(xnT, alpha, lsm, wtop);
    corr_merge<<<64, 256, 0, stream>>>(wtop, ism, out);
}